// Round 1
// baseline (702.343 us; speedup 1.0000x reference)
//
#include <hip/hip_runtime.h>
#include <hip/hip_bf16.h>
#include <math.h>

// Problem dims
#define Bb 4
#define Sdim 2048
#define Ddim 512
#define RANK 32
#define Nn16 16
#define TOK (Bb * Sdim)   // 8192

// ---------------------------------------------------------------------------
// LayerNorm: one wave per row of 512, 4 rows per 256-thread block
// ---------------------------------------------------------------------------
__global__ void ln_kernel(const float* __restrict__ x, const float* __restrict__ gamma,
                          const float* __restrict__ beta, float* __restrict__ xn) {
    int row = blockIdx.x * 4 + (threadIdx.x >> 6);
    int lane = threadIdx.x & 63;
    const float4* xr = (const float4*)(x + (size_t)row * Ddim);
    float4 v0 = xr[lane];
    float4 v1 = xr[lane + 64];
    float s = v0.x + v0.y + v0.z + v0.w + v1.x + v1.y + v1.z + v1.w;
    float q = v0.x*v0.x + v0.y*v0.y + v0.z*v0.z + v0.w*v0.w
            + v1.x*v1.x + v1.y*v1.y + v1.z*v1.z + v1.w*v1.w;
    #pragma unroll
    for (int m = 1; m <= 32; m <<= 1) { s += __shfl_xor(s, m); q += __shfl_xor(q, m); }
    float mu = s * (1.0f / Ddim);
    float var = q * (1.0f / Ddim) - mu * mu;
    float rs = rsqrtf(var + 1e-5f);
    const float4* g4 = (const float4*)gamma;
    const float4* b4 = (const float4*)beta;
    float4 g0 = g4[lane], g1 = g4[lane + 64];
    float4 be0 = b4[lane], be1 = b4[lane + 64];
    float4 o0, o1;
    o0.x = (v0.x - mu) * rs * g0.x + be0.x;
    o0.y = (v0.y - mu) * rs * g0.y + be0.y;
    o0.z = (v0.z - mu) * rs * g0.z + be0.z;
    o0.w = (v0.w - mu) * rs * g0.w + be0.w;
    o1.x = (v1.x - mu) * rs * g1.x + be1.x;
    o1.y = (v1.y - mu) * rs * g1.y + be1.y;
    o1.z = (v1.z - mu) * rs * g1.z + be1.z;
    o1.w = (v1.w - mu) * rs * g1.w + be1.w;
    float4* outr = (float4*)(xn + (size_t)row * Ddim);
    outr[lane] = o0;
    outr[lane + 64] = o1;
}

// ---------------------------------------------------------------------------
// fp32 tiled GEMM: C[M x N] = A[M x K] @ W[K x N] + bias
// 64x64 tile, BK=16, 256 threads, 4x4 per thread
// ---------------------------------------------------------------------------
__global__ void gemm_bias(const float* __restrict__ A, const float* __restrict__ W,
                          const float* __restrict__ bias, float* __restrict__ C,
                          int M, int Nw, int K) {
    __shared__ float As[16][64];
    __shared__ float Bs[16][64];
    int bm = blockIdx.y * 64, bn = blockIdx.x * 64;
    int tid = threadIdx.x;
    int tx = tid & 15, ty = tid >> 4;
    int arow = tid >> 2, acol = (tid & 3) << 2;
    int brow = tid >> 4, bcol = (tid & 15) << 2;
    float acc[4][4];
    #pragma unroll
    for (int i = 0; i < 4; ++i)
        #pragma unroll
        for (int j = 0; j < 4; ++j) acc[i][j] = 0.f;

    for (int k0 = 0; k0 < K; k0 += 16) {
        float4 av = *(const float4*)(A + (size_t)(bm + arow) * K + k0 + acol);
        float4 bv = *(const float4*)(W + (size_t)(k0 + brow) * Nw + bn + bcol);
        __syncthreads();
        As[acol + 0][arow] = av.x;
        As[acol + 1][arow] = av.y;
        As[acol + 2][arow] = av.z;
        As[acol + 3][arow] = av.w;
        *(float4*)&Bs[brow][bcol] = bv;
        __syncthreads();
        #pragma unroll
        for (int k = 0; k < 16; ++k) {
            float4 a = *(const float4*)&As[k][ty << 2];
            float4 b = *(const float4*)&Bs[k][tx << 2];
            acc[0][0] = fmaf(a.x, b.x, acc[0][0]);
            acc[0][1] = fmaf(a.x, b.y, acc[0][1]);
            acc[0][2] = fmaf(a.x, b.z, acc[0][2]);
            acc[0][3] = fmaf(a.x, b.w, acc[0][3]);
            acc[1][0] = fmaf(a.y, b.x, acc[1][0]);
            acc[1][1] = fmaf(a.y, b.y, acc[1][1]);
            acc[1][2] = fmaf(a.y, b.z, acc[1][2]);
            acc[1][3] = fmaf(a.y, b.w, acc[1][3]);
            acc[2][0] = fmaf(a.z, b.x, acc[2][0]);
            acc[2][1] = fmaf(a.z, b.y, acc[2][1]);
            acc[2][2] = fmaf(a.z, b.z, acc[2][2]);
            acc[2][3] = fmaf(a.z, b.w, acc[2][3]);
            acc[3][0] = fmaf(a.w, b.x, acc[3][0]);
            acc[3][1] = fmaf(a.w, b.y, acc[3][1]);
            acc[3][2] = fmaf(a.w, b.z, acc[3][2]);
            acc[3][3] = fmaf(a.w, b.w, acc[3][3]);
        }
    }
    float4 bias4 = make_float4(0.f, 0.f, 0.f, 0.f);
    if (bias) bias4 = *(const float4*)(bias + bn + (tx << 2));
    #pragma unroll
    for (int i = 0; i < 4; ++i) {
        float4 o;
        o.x = acc[i][0] + bias4.x;
        o.y = acc[i][1] + bias4.y;
        o.z = acc[i][2] + bias4.z;
        o.w = acc[i][3] + bias4.w;
        *(float4*)(C + (size_t)(bm + (ty << 2) + i) * Nw + bn + (tx << 2)) = o;
    }
}

// ---------------------------------------------------------------------------
// delta = softplus(dbc[:, :32] @ W_dt + b_dt)  — one token per block
// ---------------------------------------------------------------------------
__device__ __forceinline__ float softplus_f(float v) {
    return v > 20.f ? v : log1pf(__expf(v));
}

__global__ void delta_kernel(const float* __restrict__ dbc, const float* __restrict__ W_dt,
                             const float* __restrict__ b_dt, float* __restrict__ delta) {
    int t = blockIdx.x;
    __shared__ float row[RANK];
    if (threadIdx.x < RANK) row[threadIdx.x] = dbc[(size_t)t * 64 + threadIdx.x];
    __syncthreads();
    #pragma unroll
    for (int rep = 0; rep < 2; ++rep) {
        int j = threadIdx.x + rep * 256;
        float acc = b_dt[j];
        #pragma unroll
        for (int k = 0; k < RANK; ++k) acc = fmaf(row[k], W_dt[k * Ddim + j], acc);
        delta[(size_t)t * Ddim + j] = softplus_f(acc);
    }
}

// ---------------------------------------------------------------------------
// SSM scan + fused epilogue.
// grid: B * (D/8) = 256 blocks, 128 threads (2 waves). wave handles 4 d's,
// lane = dl*16 + n. Chunked LDS staging of 64 timesteps.
// out = (z1 + y) * silu(z1) + x,  y = sum_n h*C + D_ssm*bwd
// ---------------------------------------------------------------------------
__global__ void scan_kernel(const float* __restrict__ delta, const float* __restrict__ bwd,
                            const float* __restrict__ dbc, const float* __restrict__ z1,
                            const float* __restrict__ x, const float* __restrict__ A_log,
                            const float* __restrict__ D_ssm, float* __restrict__ out) {
    const int L = 64;
    int blk = blockIdx.x;
    int b = blk >> 6;          // 64 blocks per batch (D/8)
    int d0 = (blk & 63) << 3;  // 8 d's per block
    int tid = threadIdx.x;
    int w = tid >> 6;
    int lw = tid & 63;
    int dl = lw >> 4;
    int n = lw & 15;
    int dcol = (w << 2) + dl;  // 0..7
    int d = d0 + dcol;

    float A = -__expf(A_log[d * Nn16 + n]);

    __shared__ float sdelta[L][8];
    __shared__ float sbwd[L][8];
    __shared__ float sBC[L][32];
    __shared__ float sy[L][8];

    float h = 0.f;
    size_t base = ((size_t)b * Sdim) * Ddim + d0;
    int lsl = tid >> 1;            // 0..63 (row for staging/epilogue)
    int lc4 = (tid & 1) << 2;      // 0 or 4
    float4 dsv = *(const float4*)(D_ssm + d0 + lc4);

    for (int s0 = 0; s0 < Sdim; s0 += L) {
        // ---- stage global -> registers ----
        size_t rowoff = base + (size_t)(s0 + lsl) * Ddim + lc4;
        float4 dv = *(const float4*)(delta + rowoff);
        float4 bv = *(const float4*)(bwd + rowoff);
        float4 bcv[4];
        #pragma unroll
        for (int r = 0; r < 4; ++r) {
            int f = tid + r * 128;
            int sl = f >> 3, c4 = (f & 7) << 2;
            bcv[r] = *(const float4*)(dbc + ((size_t)(b * Sdim + s0 + sl)) * 64 + 32 + c4);
        }
        __syncthreads();  // prior chunk consumers done
        *(float4*)&sdelta[lsl][lc4] = dv;
        *(float4*)&sbwd[lsl][lc4] = bv;
        #pragma unroll
        for (int r = 0; r < 4; ++r) {
            int f = tid + r * 128;
            int sl = f >> 3, c4 = (f & 7) << 2;
            *(float4*)&sBC[sl][c4] = bcv[r];
        }
        __syncthreads();

        // ---- scan over chunk ----
        #pragma unroll 4
        for (int sl = 0; sl < L; ++sl) {
            float dlt = sdelta[sl][dcol];
            float bw = sbwd[sl][dcol];
            float Bn = sBC[sl][n];
            float Cn = sBC[sl][16 + n];
            float dA = __expf(dlt * A);
            h = fmaf(dA, h, dlt * bw * Bn);
            float t = h * Cn;
            t += __shfl_xor(t, 1);
            t += __shfl_xor(t, 2);
            t += __shfl_xor(t, 4);
            t += __shfl_xor(t, 8);
            if (n == 0) sy[sl][dcol] = t;
        }
        __syncthreads();

        // ---- fused epilogue: out = (z1 + y)*silu(z1) + x ----
        float4 yv = *(const float4*)&sy[lsl][lc4];
        float4 bwv = *(const float4*)&sbwd[lsl][lc4];
        float4 z1v = *(const float4*)(z1 + rowoff);
        float4 xv = *(const float4*)(x + rowoff);
        float4 o;
        {
            float y0 = yv.x + dsv.x * bwv.x;
            float y1 = yv.y + dsv.y * bwv.y;
            float y2 = yv.z + dsv.z * bwv.z;
            float y3 = yv.w + dsv.w * bwv.w;
            float sg0 = z1v.x / (1.f + __expf(-z1v.x));
            float sg1 = z1v.y / (1.f + __expf(-z1v.y));
            float sg2 = z1v.z / (1.f + __expf(-z1v.z));
            float sg3 = z1v.w / (1.f + __expf(-z1v.w));
            o.x = (z1v.x + y0) * sg0 + xv.x;
            o.y = (z1v.y + y1) * sg1 + xv.y;
            o.z = (z1v.z + y2) * sg2 + xv.z;
            o.w = (z1v.w + y3) * sg3 + xv.w;
        }
        *(float4*)(out + rowoff) = o;
    }
}

// ---------------------------------------------------------------------------
extern "C" void kernel_launch(void* const* d_in, const int* in_sizes, int n_in,
                              void* d_out, int out_size, void* d_ws, size_t ws_size,
                              hipStream_t stream) {
    const float* x      = (const float*)d_in[0];
    const float* gamma  = (const float*)d_in[1];
    const float* beta   = (const float*)d_in[2];
    const float* W_proj = (const float*)d_in[3];
    const float* b_proj = (const float*)d_in[4];
    // d_in[5]=W_fwd, d_in[6]=b_fwd are dead code in the reference (x1_ssm unused)
    const float* W_bwd  = (const float*)d_in[7];
    const float* b_bwd  = (const float*)d_in[8];
    const float* W_dbc  = (const float*)d_in[9];
    const float* W_dt   = (const float*)d_in[10];
    const float* b_dt   = (const float*)d_in[11];
    const float* A_log  = (const float*)d_in[12];
    const float* D_ssm  = (const float*)d_in[13];
    float* out = (float*)d_out;

    const size_t MAT = (size_t)TOK * Ddim;   // 4.19M floats = 16 MB
    float* xn    = (float*)d_ws;             // reused as delta later
    float* z1    = xn + MAT;
    float* bwd   = z1 + MAT;
    float* dbc   = bwd + MAT;                // TOK*64 = 2 MB
    float* delta = xn;                       // xn dead after GEMM1

    // 1. LayerNorm
    ln_kernel<<<dim3(TOK / 4), dim3(256), 0, stream>>>(x, gamma, beta, xn);
    // 2. z1 = xn @ W_proj + b_proj
    gemm_bias<<<dim3(Ddim / 64, TOK / 64), dim3(256), 0, stream>>>(xn, W_proj, b_proj, z1, TOK, Ddim, Ddim);
    // 3. bwd = z1 @ W_bwd + b_bwd
    gemm_bias<<<dim3(Ddim / 64, TOK / 64), dim3(256), 0, stream>>>(z1, W_bwd, b_bwd, bwd, TOK, Ddim, Ddim);
    // 4. dbc = bwd @ W_dbc (no bias)
    gemm_bias<<<dim3(1, TOK / 64), dim3(256), 0, stream>>>(bwd, W_dbc, nullptr, dbc, TOK, 64, Ddim);
    // 5. delta = softplus(dbc[:, :32] @ W_dt + b_dt)
    delta_kernel<<<dim3(TOK), dim3(256), 0, stream>>>(dbc, W_dt, b_dt, delta);
    // 6. SSM scan + fused epilogue
    scan_kernel<<<dim3(Bb * (Ddim / 8)), dim3(128), 0, stream>>>(delta, bwd, dbc, z1, x, A_log, D_ssm, out);
}

// Round 2
// 319.156 us; speedup vs baseline: 2.2006x; 2.2006x over previous
//
#include <hip/hip_runtime.h>
#include <hip/hip_bf16.h>
#include <math.h>

// Problem dims
#define Bb 4
#define Sdim 2048
#define Ddim 512
#define RANK 32
#define Nn16 16
#define TOK (Bb * Sdim)   // 8192
#define NCh 64            // chunks along S
#define LCh (Sdim / NCh)  // 32 steps per chunk

// ---------------------------------------------------------------------------
// LayerNorm: one wave per row of 512, 4 rows per 256-thread block
// ---------------------------------------------------------------------------
__global__ void ln_kernel(const float* __restrict__ x, const float* __restrict__ gamma,
                          const float* __restrict__ beta, float* __restrict__ xn) {
    int row = blockIdx.x * 4 + (threadIdx.x >> 6);
    int lane = threadIdx.x & 63;
    const float4* xr = (const float4*)(x + (size_t)row * Ddim);
    float4 v0 = xr[lane];
    float4 v1 = xr[lane + 64];
    float s = v0.x + v0.y + v0.z + v0.w + v1.x + v1.y + v1.z + v1.w;
    float q = v0.x*v0.x + v0.y*v0.y + v0.z*v0.z + v0.w*v0.w
            + v1.x*v1.x + v1.y*v1.y + v1.z*v1.z + v1.w*v1.w;
    #pragma unroll
    for (int m = 1; m <= 32; m <<= 1) { s += __shfl_xor(s, m); q += __shfl_xor(q, m); }
    float mu = s * (1.0f / Ddim);
    float var = q * (1.0f / Ddim) - mu * mu;
    float rs = rsqrtf(var + 1e-5f);
    const float4* g4 = (const float4*)gamma;
    const float4* b4 = (const float4*)beta;
    float4 g0 = g4[lane], g1 = g4[lane + 64];
    float4 be0 = b4[lane], be1 = b4[lane + 64];
    float4 o0, o1;
    o0.x = (v0.x - mu) * rs * g0.x + be0.x;
    o0.y = (v0.y - mu) * rs * g0.y + be0.y;
    o0.z = (v0.z - mu) * rs * g0.z + be0.z;
    o0.w = (v0.w - mu) * rs * g0.w + be0.w;
    o1.x = (v1.x - mu) * rs * g1.x + be1.x;
    o1.y = (v1.y - mu) * rs * g1.y + be1.y;
    o1.z = (v1.z - mu) * rs * g1.z + be1.z;
    o1.w = (v1.w - mu) * rs * g1.w + be1.w;
    float4* outr = (float4*)(xn + (size_t)row * Ddim);
    outr[lane] = o0;
    outr[lane + 64] = o1;
}

// ---------------------------------------------------------------------------
// fp32 tiled GEMM: C[M x N] = A[M x K] @ W[K x N] + bias
// ---------------------------------------------------------------------------
__global__ void gemm_bias(const float* __restrict__ A, const float* __restrict__ W,
                          const float* __restrict__ bias, float* __restrict__ C,
                          int M, int Nw, int K) {
    __shared__ float As[16][64];
    __shared__ float Bs[16][64];
    int bm = blockIdx.y * 64, bn = blockIdx.x * 64;
    int tid = threadIdx.x;
    int tx = tid & 15, ty = tid >> 4;
    int arow = tid >> 2, acol = (tid & 3) << 2;
    int brow = tid >> 4, bcol = (tid & 15) << 2;
    float acc[4][4];
    #pragma unroll
    for (int i = 0; i < 4; ++i)
        #pragma unroll
        for (int j = 0; j < 4; ++j) acc[i][j] = 0.f;

    for (int k0 = 0; k0 < K; k0 += 16) {
        float4 av = *(const float4*)(A + (size_t)(bm + arow) * K + k0 + acol);
        float4 bv = *(const float4*)(W + (size_t)(k0 + brow) * Nw + bn + bcol);
        __syncthreads();
        As[acol + 0][arow] = av.x;
        As[acol + 1][arow] = av.y;
        As[acol + 2][arow] = av.z;
        As[acol + 3][arow] = av.w;
        *(float4*)&Bs[brow][bcol] = bv;
        __syncthreads();
        #pragma unroll
        for (int k = 0; k < 16; ++k) {
            float4 a = *(const float4*)&As[k][ty << 2];
            float4 b = *(const float4*)&Bs[k][tx << 2];
            acc[0][0] = fmaf(a.x, b.x, acc[0][0]);
            acc[0][1] = fmaf(a.x, b.y, acc[0][1]);
            acc[0][2] = fmaf(a.x, b.z, acc[0][2]);
            acc[0][3] = fmaf(a.x, b.w, acc[0][3]);
            acc[1][0] = fmaf(a.y, b.x, acc[1][0]);
            acc[1][1] = fmaf(a.y, b.y, acc[1][1]);
            acc[1][2] = fmaf(a.y, b.z, acc[1][2]);
            acc[1][3] = fmaf(a.y, b.w, acc[1][3]);
            acc[2][0] = fmaf(a.z, b.x, acc[2][0]);
            acc[2][1] = fmaf(a.z, b.y, acc[2][1]);
            acc[2][2] = fmaf(a.z, b.z, acc[2][2]);
            acc[2][3] = fmaf(a.z, b.w, acc[2][3]);
            acc[3][0] = fmaf(a.w, b.x, acc[3][0]);
            acc[3][1] = fmaf(a.w, b.y, acc[3][1]);
            acc[3][2] = fmaf(a.w, b.z, acc[3][2]);
            acc[3][3] = fmaf(a.w, b.w, acc[3][3]);
        }
    }
    float4 bias4 = make_float4(0.f, 0.f, 0.f, 0.f);
    if (bias) bias4 = *(const float4*)(bias + bn + (tx << 2));
    #pragma unroll
    for (int i = 0; i < 4; ++i) {
        float4 o;
        o.x = acc[i][0] + bias4.x;
        o.y = acc[i][1] + bias4.y;
        o.z = acc[i][2] + bias4.z;
        o.w = acc[i][3] + bias4.w;
        *(float4*)(C + (size_t)(bm + (ty << 2) + i) * Nw + bn + (tx << 2)) = o;
    }
}

// ---------------------------------------------------------------------------
// delta = softplus(dbc[:, :32] @ W_dt + b_dt)  — one token per block
// ---------------------------------------------------------------------------
__device__ __forceinline__ float softplus_f(float v) {
    return v > 20.f ? v : log1pf(__expf(v));
}

__global__ void delta_kernel(const float* __restrict__ dbc, const float* __restrict__ W_dt,
                             const float* __restrict__ b_dt, float* __restrict__ delta) {
    int t = blockIdx.x;
    __shared__ float row[RANK];
    if (threadIdx.x < RANK) row[threadIdx.x] = dbc[(size_t)t * 64 + threadIdx.x];
    __syncthreads();
    #pragma unroll
    for (int rep = 0; rep < 2; ++rep) {
        int j = threadIdx.x + rep * 256;
        float acc = b_dt[j];
        #pragma unroll
        for (int k = 0; k < RANK; ++k) acc = fmaf(row[k], W_dt[k * Ddim + j], acc);
        delta[(size_t)t * Ddim + j] = softplus_f(acc);
    }
}

// ---------------------------------------------------------------------------
// Chunked parallel scan. Lane owns one d; h[16] (over n) lives in registers.
// pass1: per-chunk local scan from h=0 -> chunk-final h (hend) + sum(delta) (sdbuf)
// pass2: serial combine over chunks per (b,d,n); hend becomes h_in per chunk
// pass3: redo local scan seeded with h_in, fused y-reduction + SiLU epilogue
// ---------------------------------------------------------------------------
__global__ __launch_bounds__(256) void scan_pass1(
    const float* __restrict__ delta, const float* __restrict__ bwd,
    const float* __restrict__ dbc, const float* __restrict__ A_log,
    float* __restrict__ hend, float* __restrict__ sdbuf)
{
    int d = (blockIdx.x << 8) + threadIdx.x;
    int c = blockIdx.y;
    int b = blockIdx.z;

    float A[16];
    {
        const float4* al = (const float4*)(A_log + (size_t)d * 16);
        #pragma unroll
        for (int i = 0; i < 4; ++i) {
            float4 v = al[i];
            A[4*i+0] = -__expf(v.x); A[4*i+1] = -__expf(v.y);
            A[4*i+2] = -__expf(v.z); A[4*i+3] = -__expf(v.w);
        }
    }
    float h[16];
    #pragma unroll
    for (int n = 0; n < 16; ++n) h[n] = 0.f;
    float sd = 0.f;

    size_t base = ((size_t)(b * Sdim + c * LCh)) * Ddim + d;
    const float* dbcrow = dbc + ((size_t)(b * Sdim + c * LCh)) * 64 + 32;

    #pragma unroll 2
    for (int i = 0; i < LCh; ++i) {
        float dlt = delta[base + (size_t)i * Ddim];
        float bw  = bwd [base + (size_t)i * Ddim];
        float4 B0 = *(const float4*)(dbcrow + i * 64 + 0);
        float4 B1 = *(const float4*)(dbcrow + i * 64 + 4);
        float4 B2 = *(const float4*)(dbcrow + i * 64 + 8);
        float4 B3 = *(const float4*)(dbcrow + i * 64 + 12);
        sd += dlt;
        float xb = dlt * bw;
        float Bv[16] = {B0.x,B0.y,B0.z,B0.w, B1.x,B1.y,B1.z,B1.w,
                        B2.x,B2.y,B2.z,B2.w, B3.x,B3.y,B3.z,B3.w};
        #pragma unroll
        for (int n = 0; n < 16; ++n)
            h[n] = fmaf(__expf(dlt * A[n]), h[n], xb * Bv[n]);
    }
    size_t cidx = ((((size_t)b * NCh + c) * Ddim) + d) * 16;
    float4* ho = (float4*)(hend + cidx);
    ho[0] = make_float4(h[0],  h[1],  h[2],  h[3]);
    ho[1] = make_float4(h[4],  h[5],  h[6],  h[7]);
    ho[2] = make_float4(h[8],  h[9],  h[10], h[11]);
    ho[3] = make_float4(h[12], h[13], h[14], h[15]);
    sdbuf[((size_t)b * NCh + c) * Ddim + d] = sd;
}

__global__ __launch_bounds__(256) void scan_pass2(
    float* __restrict__ hend, const float* __restrict__ sdbuf,
    const float* __restrict__ A_log)
{
    int gl = blockIdx.x * 256 + threadIdx.x;
    int b = gl >> 13;          // D*N = 8192 per batch
    int r = gl & 8191;         // d*16 + n
    int d = r >> 4;
    float A = -__expf(A_log[r]);
    float hin = 0.f;
    for (int c = 0; c < NCh; ++c) {
        size_t idx = (((size_t)b * NCh + c) * Ddim) * 16 + r;
        float he  = hend[idx];
        float sdv = sdbuf[((size_t)b * NCh + c) * Ddim + d];
        hend[idx] = hin;                         // in-place: now h_in for chunk c
        hin = fmaf(__expf(A * sdv), hin, he);    // carry across chunk c
    }
}

// NOTE: bwd and out intentionally NOT __restrict__ — they alias (bwd lives in
// d_out to stay inside the known-safe workspace). Each lane reads bwd[t][d]
// strictly before writing out[t][d]; (t,d) ownership is exclusive per lane.
__global__ __launch_bounds__(256) void scan_pass3(
    const float* __restrict__ delta, const float* bwd,
    const float* __restrict__ dbc, const float* __restrict__ z1,
    const float* __restrict__ x, const float* __restrict__ A_log,
    const float* __restrict__ D_ssm, const float* __restrict__ hin,
    float* out)
{
    int d = (blockIdx.x << 8) + threadIdx.x;
    int c = blockIdx.y;
    int b = blockIdx.z;

    float A[16];
    {
        const float4* al = (const float4*)(A_log + (size_t)d * 16);
        #pragma unroll
        for (int i = 0; i < 4; ++i) {
            float4 v = al[i];
            A[4*i+0] = -__expf(v.x); A[4*i+1] = -__expf(v.y);
            A[4*i+2] = -__expf(v.z); A[4*i+3] = -__expf(v.w);
        }
    }
    float h[16];
    {
        size_t cidx = ((((size_t)b * NCh + c) * Ddim) + d) * 16;
        const float4* hi = (const float4*)(hin + cidx);
        float4 h0 = hi[0], h1 = hi[1], h2 = hi[2], h3 = hi[3];
        h[0]=h0.x; h[1]=h0.y; h[2]=h0.z; h[3]=h0.w;
        h[4]=h1.x; h[5]=h1.y; h[6]=h1.z; h[7]=h1.w;
        h[8]=h2.x; h[9]=h2.y; h[10]=h2.z; h[11]=h2.w;
        h[12]=h3.x; h[13]=h3.y; h[14]=h3.z; h[15]=h3.w;
    }
    float Dd = D_ssm[d];

    size_t base = ((size_t)(b * Sdim + c * LCh)) * Ddim + d;
    const float* dbcrow = dbc + ((size_t)(b * Sdim + c * LCh)) * 64 + 32;

    #pragma unroll 2
    for (int i = 0; i < LCh; ++i) {
        float dlt = delta[base + (size_t)i * Ddim];
        float bw  = bwd [base + (size_t)i * Ddim];
        float z1v = z1  [base + (size_t)i * Ddim];
        float xv  = x   [base + (size_t)i * Ddim];
        float4 B0 = *(const float4*)(dbcrow + i * 64 + 0);
        float4 B1 = *(const float4*)(dbcrow + i * 64 + 4);
        float4 B2 = *(const float4*)(dbcrow + i * 64 + 8);
        float4 B3 = *(const float4*)(dbcrow + i * 64 + 12);
        float4 C0 = *(const float4*)(dbcrow + i * 64 + 16);
        float4 C1 = *(const float4*)(dbcrow + i * 64 + 20);
        float4 C2 = *(const float4*)(dbcrow + i * 64 + 24);
        float4 C3 = *(const float4*)(dbcrow + i * 64 + 28);
        float Bv[16] = {B0.x,B0.y,B0.z,B0.w, B1.x,B1.y,B1.z,B1.w,
                        B2.x,B2.y,B2.z,B2.w, B3.x,B3.y,B3.z,B3.w};
        float Cv[16] = {C0.x,C0.y,C0.z,C0.w, C1.x,C1.y,C1.z,C1.w,
                        C2.x,C2.y,C2.z,C2.w, C3.x,C3.y,C3.z,C3.w};
        float xb = dlt * bw;
        float y  = Dd * bw;
        #pragma unroll
        for (int n = 0; n < 16; ++n) {
            h[n] = fmaf(__expf(dlt * A[n]), h[n], xb * Bv[n]);
            y = fmaf(h[n], Cv[n], y);
        }
        float silu = z1v / (1.f + __expf(-z1v));
        out[base + (size_t)i * Ddim] = fmaf(z1v + y, silu, xv);
    }
}

// ---------------------------------------------------------------------------
extern "C" void kernel_launch(void* const* d_in, const int* in_sizes, int n_in,
                              void* d_out, int out_size, void* d_ws, size_t ws_size,
                              hipStream_t stream) {
    const float* x      = (const float*)d_in[0];
    const float* gamma  = (const float*)d_in[1];
    const float* beta   = (const float*)d_in[2];
    const float* W_proj = (const float*)d_in[3];
    const float* b_proj = (const float*)d_in[4];
    // d_in[5]=W_fwd, d_in[6]=b_fwd are dead code in the reference (x1_ssm unused)
    const float* W_bwd  = (const float*)d_in[7];
    const float* b_bwd  = (const float*)d_in[8];
    const float* W_dbc  = (const float*)d_in[9];
    const float* W_dt   = (const float*)d_in[10];
    const float* b_dt   = (const float*)d_in[11];
    const float* A_log  = (const float*)d_in[12];
    const float* D_ssm  = (const float*)d_in[13];
    float* out = (float*)d_out;

    const size_t MAT = (size_t)TOK * Ddim;   // 4.19M floats = 16 MB
    float* xn    = (float*)d_ws;             // reused as delta after GEMM1
    float* z1    = xn + MAT;
    float* dbc   = z1 + MAT;                 // TOK*64 = 2 MB
    float* hend  = dbc + (size_t)TOK * 64;   // B*NC*D*16 = 8 MB
    float* sdbuf = hend + (size_t)Bb * NCh * Ddim * 16;  // 0.5 MB
    float* delta = xn;
    float* bwd   = out;                      // bwd lives in d_out (see pass3 note)

    // 1. LayerNorm
    ln_kernel<<<dim3(TOK / 4), dim3(256), 0, stream>>>(x, gamma, beta, xn);
    // 2. z1 = xn @ W_proj + b_proj
    gemm_bias<<<dim3(Ddim / 64, TOK / 64), dim3(256), 0, stream>>>(xn, W_proj, b_proj, z1, TOK, Ddim, Ddim);
    // 3. bwd = z1 @ W_bwd + b_bwd   (into d_out)
    gemm_bias<<<dim3(Ddim / 64, TOK / 64), dim3(256), 0, stream>>>(z1, W_bwd, b_bwd, bwd, TOK, Ddim, Ddim);
    // 4. dbc = bwd @ W_dbc (no bias)
    gemm_bias<<<dim3(1, TOK / 64), dim3(256), 0, stream>>>(bwd, W_dbc, nullptr, dbc, TOK, 64, Ddim);
    // 5. delta = softplus(dbc[:, :32] @ W_dt + b_dt)   (into xn)
    delta_kernel<<<dim3(TOK), dim3(256), 0, stream>>>(dbc, W_dt, b_dt, delta);
    // 6. Chunked scan
    scan_pass1<<<dim3(2, NCh, Bb), dim3(256), 0, stream>>>(delta, bwd, dbc, A_log, hend, sdbuf);
    scan_pass2<<<dim3(Bb * Ddim * Nn16 / 256), dim3(256), 0, stream>>>(hend, sdbuf, A_log);
    scan_pass3<<<dim3(2, NCh, Bb), dim3(256), 0, stream>>>(delta, bwd, dbc, z1, x, A_log, D_ssm, hend, out);
}

// Round 3
// 272.180 us; speedup vs baseline: 2.5804x; 1.1726x over previous
//
#include <hip/hip_runtime.h>
#include <hip/hip_bf16.h>
#include <math.h>

// Problem dims
#define Bb 4
#define Sdim 2048
#define Ddim 512
#define RANK 32
#define Nn16 16
#define TOK (Bb * Sdim)   // 8192
#define NCh 64            // chunks along S
#define LCh (Sdim / NCh)  // 32 steps per chunk

using bf16x8 = __attribute__((ext_vector_type(8))) __bf16;
using f32x4  = __attribute__((ext_vector_type(4))) float;

__device__ __forceinline__ unsigned short f2bf(float f) {
    unsigned int u = __float_as_uint(f);
    u += 0x7fffu + ((u >> 16) & 1u);
    return (unsigned short)(u >> 16);
}
__device__ __forceinline__ float bf2f(unsigned short h) {
    return __uint_as_float(((unsigned int)h) << 16);
}

// async global->LDS, 16B per lane; lds base must be wave-uniform
#define GLD16(g, l) __builtin_amdgcn_global_load_lds( \
    (const __attribute__((address_space(1))) void*)(g), \
    (__attribute__((address_space(3))) void*)(l), 16, 0, 0)

// ---------------------------------------------------------------------------
// LayerNorm -> bf16 output. One wave per row of 512, 4 rows / 256-thr block.
// ---------------------------------------------------------------------------
__global__ void ln_kernel(const float* __restrict__ x, const float* __restrict__ gamma,
                          const float* __restrict__ beta, ushort* __restrict__ xn) {
    int row = blockIdx.x * 4 + (threadIdx.x >> 6);
    int lane = threadIdx.x & 63;
    const float4* xr = (const float4*)(x + (size_t)row * Ddim);
    float4 v0 = xr[lane];
    float4 v1 = xr[lane + 64];
    float s = v0.x + v0.y + v0.z + v0.w + v1.x + v1.y + v1.z + v1.w;
    float q = v0.x*v0.x + v0.y*v0.y + v0.z*v0.z + v0.w*v0.w
            + v1.x*v1.x + v1.y*v1.y + v1.z*v1.z + v1.w*v1.w;
    #pragma unroll
    for (int m = 1; m <= 32; m <<= 1) { s += __shfl_xor(s, m); q += __shfl_xor(q, m); }
    float mu = s * (1.0f / Ddim);
    float var = q * (1.0f / Ddim) - mu * mu;
    float rs = rsqrtf(var + 1e-5f);
    const float4* g4 = (const float4*)gamma;
    const float4* b4 = (const float4*)beta;
    float4 g0 = g4[lane], g1 = g4[lane + 64];
    float4 be0 = b4[lane], be1 = b4[lane + 64];
    ushort4 u0, u1;
    u0.x = f2bf((v0.x - mu) * rs * g0.x + be0.x);
    u0.y = f2bf((v0.y - mu) * rs * g0.y + be0.y);
    u0.z = f2bf((v0.z - mu) * rs * g0.z + be0.z);
    u0.w = f2bf((v0.w - mu) * rs * g0.w + be0.w);
    u1.x = f2bf((v1.x - mu) * rs * g1.x + be1.x);
    u1.y = f2bf((v1.y - mu) * rs * g1.y + be1.y);
    u1.z = f2bf((v1.z - mu) * rs * g1.z + be1.z);
    u1.w = f2bf((v1.w - mu) * rs * g1.w + be1.w);
    *(ushort4*)(xn + (size_t)row * Ddim + lane * 4) = u0;
    *(ushort4*)(xn + (size_t)row * Ddim + 256 + lane * 4) = u1;
}

// ---------------------------------------------------------------------------
// Transpose fp32 [K][N] -> bf16 [N][K]
// ---------------------------------------------------------------------------
__global__ void transpose_bf16(const float* __restrict__ in, ushort* __restrict__ out,
                               int K, int N) {
    __shared__ float t[32][33];
    int bx = blockIdx.x * 32, by = blockIdx.y * 32;   // bx: N, by: K
    int x = threadIdx.x & 31, y = threadIdx.x >> 5;   // 256 threads, y=0..7
    #pragma unroll
    for (int yy = y; yy < 32; yy += 8)
        t[yy][x] = in[(size_t)(by + yy) * N + bx + x];
    __syncthreads();
    #pragma unroll
    for (int yy = y; yy < 32; yy += 8)
        out[(size_t)(bx + yy) * K + by + x] = f2bf(t[x][yy]);
}

// ---------------------------------------------------------------------------
// bf16 MFMA GEMM, 128x128 tile, BK=32, B given transposed [N][K].
// C fp32 (+bias), optional Cb bf16 mirror.
// Layouts (m89/m97-verified): A-frag A[m=lane&15][k=quad*8+j];
// B^T-frag identical; C/D col=lane&15, row=quad*4+reg.
// ---------------------------------------------------------------------------
__global__ __launch_bounds__(256) void gemm_mfma_128(
    const ushort* __restrict__ A,  // [M][K] bf16
    const ushort* __restrict__ Bt, // [N][K] bf16
    const float* __restrict__ bias,
    float* __restrict__ C, ushort* __restrict__ Cb,
    int Nw, int K)
{
    __shared__ __align__(16) ushort As[128 * 32];
    __shared__ __align__(16) ushort Bs[128 * 32];
    int tid = threadIdx.x, w = tid >> 6, lane = tid & 63;
    int bm = blockIdx.y * 128, bn = blockIdx.x * 128;
    int wm = (w & 1) * 64, wn = (w >> 1) * 64;
    int quad = lane >> 4, l16 = lane & 15;
    int srow = lane >> 2, schunk = (lane & 3) * 8;   // staging: 16 rows x 4 chunks
    f32x4 acc[4][4] = {};

    for (int k0 = 0; k0 < K; k0 += 32) {
        __syncthreads();   // prior iter's consumers done
        #pragma unroll
        for (int s = 0; s < 2; ++s) {
            int r = w * 32 + s * 16;   // wave-uniform LDS base
            GLD16(A  + (size_t)(bm + r + srow) * K + k0 + schunk, &As[r * 32]);
            GLD16(Bt + (size_t)(bn + r + srow) * K + k0 + schunk, &Bs[r * 32]);
        }
        __syncthreads();   // compiler drains vmcnt before barrier
        bf16x8 af[4], bfr[4];
        #pragma unroll
        for (int i = 0; i < 4; ++i)
            af[i] = *(const bf16x8*)(const void*)&As[(wm + 16 * i + l16) * 32 + quad * 8];
        #pragma unroll
        for (int j = 0; j < 4; ++j)
            bfr[j] = *(const bf16x8*)(const void*)&Bs[(wn + 16 * j + l16) * 32 + quad * 8];
        #pragma unroll
        for (int i = 0; i < 4; ++i)
            #pragma unroll
            for (int j = 0; j < 4; ++j)
                acc[i][j] = __builtin_amdgcn_mfma_f32_16x16x32_bf16(af[i], bfr[j], acc[i][j], 0, 0, 0);
    }

    #pragma unroll
    for (int i = 0; i < 4; ++i) {
        int row = bm + wm + 16 * i + quad * 4;
        #pragma unroll
        for (int j = 0; j < 4; ++j) {
            int col = bn + wn + 16 * j + l16;
            float bv = bias ? bias[col] : 0.f;
            #pragma unroll
            for (int r = 0; r < 4; ++r) {
                float v = acc[i][j][r] + bv;
                C[(size_t)(row + r) * Nw + col] = v;
                if (Cb) Cb[(size_t)(row + r) * Nw + col] = f2bf(v);
            }
        }
    }
}

// ---------------------------------------------------------------------------
// bf16 MFMA GEMM, 128x64 tile (for dbc: N=64). No bias, fp32 out.
// ---------------------------------------------------------------------------
__global__ __launch_bounds__(256) void gemm_mfma_n64(
    const ushort* __restrict__ A,  // [M][K]
    const ushort* __restrict__ Bt, // [64][K]
    float* __restrict__ C, int K)
{
    __shared__ __align__(16) ushort As[128 * 32];
    __shared__ __align__(16) ushort Bs[64 * 32];
    int tid = threadIdx.x, w = tid >> 6, lane = tid & 63;
    int bm = blockIdx.y * 128;
    int wm = w * 32;
    int quad = lane >> 4, l16 = lane & 15;
    int srow = lane >> 2, schunk = (lane & 3) * 8;
    f32x4 acc[2][4] = {};

    for (int k0 = 0; k0 < K; k0 += 32) {
        __syncthreads();
        #pragma unroll
        for (int s = 0; s < 2; ++s) {
            int r = w * 32 + s * 16;
            GLD16(A + (size_t)(bm + r + srow) * K + k0 + schunk, &As[r * 32]);
        }
        {
            int r = w * 16;
            GLD16(Bt + (size_t)(r + srow) * K + k0 + schunk, &Bs[r * 32]);
        }
        __syncthreads();
        bf16x8 af[2], bfr[4];
        #pragma unroll
        for (int i = 0; i < 2; ++i)
            af[i] = *(const bf16x8*)(const void*)&As[(wm + 16 * i + l16) * 32 + quad * 8];
        #pragma unroll
        for (int j = 0; j < 4; ++j)
            bfr[j] = *(const bf16x8*)(const void*)&Bs[(16 * j + l16) * 32 + quad * 8];
        #pragma unroll
        for (int i = 0; i < 2; ++i)
            #pragma unroll
            for (int j = 0; j < 4; ++j)
                acc[i][j] = __builtin_amdgcn_mfma_f32_16x16x32_bf16(af[i], bfr[j], acc[i][j], 0, 0, 0);
    }
    #pragma unroll
    for (int i = 0; i < 2; ++i) {
        int row = bm + wm + 16 * i + quad * 4;
        #pragma unroll
        for (int j = 0; j < 4; ++j) {
            int col = 16 * j + l16;
            #pragma unroll
            for (int r = 0; r < 4; ++r)
                C[(size_t)(row + r) * 64 + col] = acc[i][j][r];
        }
    }
}

// ---------------------------------------------------------------------------
// delta = softplus(dbc[:, :32] @ W_dt + b_dt)
// Block = 64 tokens; W_dt staged once in LDS (bf16); dbc row in registers.
// ---------------------------------------------------------------------------
__device__ __forceinline__ float softplus_f(float v) {
    return v > 20.f ? v : log1pf(__expf(v));
}

__global__ __launch_bounds__(256) void delta_kernel2(
    const float* __restrict__ dbc, const float* __restrict__ W_dt,
    const float* __restrict__ b_dt, float* __restrict__ delta)
{
    __shared__ ushort sW[RANK * Ddim];      // 32 KB
    __shared__ float sD[64][RANK];          // 8 KB
    int tid = threadIdx.x;
    int t0 = blockIdx.x * 64;
    #pragma unroll
    for (int r = 0; r < 64; ++r) {
        int idx = r * 256 + tid;
        sW[idx] = f2bf(W_dt[idx]);
    }
    #pragma unroll
    for (int r = 0; r < 8; ++r) {
        int idx = r * 256 + tid;            // 0..2047
        int tt = idx >> 5, k = idx & 31;
        sD[tt][k] = dbc[(size_t)(t0 + tt) * 64 + k];
    }
    __syncthreads();
    int tl = tid >> 2;
    int t = t0 + tl;
    int jb = tid & 3;
    float dv[RANK];
    #pragma unroll
    for (int k = 0; k < RANK; ++k) dv[k] = sD[tl][k];
    for (int jj = 0; jj < 128; ++jj) {
        int j = jb + jj * 4;
        float acc = b_dt[j];
        #pragma unroll
        for (int k = 0; k < RANK; ++k)
            acc = fmaf(dv[k], bf2f(sW[k * Ddim + j]), acc);
        delta[(size_t)t * Ddim + j] = softplus_f(acc);
    }
}

// ---------------------------------------------------------------------------
// Chunked parallel scan (unchanged from round 2).
// ---------------------------------------------------------------------------
__global__ __launch_bounds__(256) void scan_pass1(
    const float* __restrict__ delta, const float* __restrict__ bwd,
    const float* __restrict__ dbc, const float* __restrict__ A_log,
    float* __restrict__ hend, float* __restrict__ sdbuf)
{
    int d = (blockIdx.x << 8) + threadIdx.x;
    int c = blockIdx.y;
    int b = blockIdx.z;

    float A[16];
    {
        const float4* al = (const float4*)(A_log + (size_t)d * 16);
        #pragma unroll
        for (int i = 0; i < 4; ++i) {
            float4 v = al[i];
            A[4*i+0] = -__expf(v.x); A[4*i+1] = -__expf(v.y);
            A[4*i+2] = -__expf(v.z); A[4*i+3] = -__expf(v.w);
        }
    }
    float h[16];
    #pragma unroll
    for (int n = 0; n < 16; ++n) h[n] = 0.f;
    float sd = 0.f;

    size_t base = ((size_t)(b * Sdim + c * LCh)) * Ddim + d;
    const float* dbcrow = dbc + ((size_t)(b * Sdim + c * LCh)) * 64 + 32;

    #pragma unroll 2
    for (int i = 0; i < LCh; ++i) {
        float dlt = delta[base + (size_t)i * Ddim];
        float bw  = bwd [base + (size_t)i * Ddim];
        float4 B0 = *(const float4*)(dbcrow + i * 64 + 0);
        float4 B1 = *(const float4*)(dbcrow + i * 64 + 4);
        float4 B2 = *(const float4*)(dbcrow + i * 64 + 8);
        float4 B3 = *(const float4*)(dbcrow + i * 64 + 12);
        sd += dlt;
        float xb = dlt * bw;
        float Bv[16] = {B0.x,B0.y,B0.z,B0.w, B1.x,B1.y,B1.z,B1.w,
                        B2.x,B2.y,B2.z,B2.w, B3.x,B3.y,B3.z,B3.w};
        #pragma unroll
        for (int n = 0; n < 16; ++n)
            h[n] = fmaf(__expf(dlt * A[n]), h[n], xb * Bv[n]);
    }
    size_t cidx = ((((size_t)b * NCh + c) * Ddim) + d) * 16;
    float4* ho = (float4*)(hend + cidx);
    ho[0] = make_float4(h[0],  h[1],  h[2],  h[3]);
    ho[1] = make_float4(h[4],  h[5],  h[6],  h[7]);
    ho[2] = make_float4(h[8],  h[9],  h[10], h[11]);
    ho[3] = make_float4(h[12], h[13], h[14], h[15]);
    sdbuf[((size_t)b * NCh + c) * Ddim + d] = sd;
}

__global__ __launch_bounds__(256) void scan_pass2(
    float* __restrict__ hend, const float* __restrict__ sdbuf,
    const float* __restrict__ A_log)
{
    int gl = blockIdx.x * 256 + threadIdx.x;
    int b = gl >> 13;
    int r = gl & 8191;
    int d = r >> 4;
    float A = -__expf(A_log[r]);
    float hin = 0.f;
    for (int c = 0; c < NCh; ++c) {
        size_t idx = (((size_t)b * NCh + c) * Ddim) * 16 + r;
        float he  = hend[idx];
        float sdv = sdbuf[((size_t)b * NCh + c) * Ddim + d];
        hend[idx] = hin;
        hin = fmaf(__expf(A * sdv), hin, he);
    }
}

// bwd/out alias (bwd lives in d_out); read-before-write per exclusive (t,d).
__global__ __launch_bounds__(256) void scan_pass3(
    const float* __restrict__ delta, const float* bwd,
    const float* __restrict__ dbc, const float* __restrict__ z1,
    const float* __restrict__ x, const float* __restrict__ A_log,
    const float* __restrict__ D_ssm, const float* __restrict__ hin,
    float* out)
{
    int d = (blockIdx.x << 8) + threadIdx.x;
    int c = blockIdx.y;
    int b = blockIdx.z;

    float A[16];
    {
        const float4* al = (const float4*)(A_log + (size_t)d * 16);
        #pragma unroll
        for (int i = 0; i < 4; ++i) {
            float4 v = al[i];
            A[4*i+0] = -__expf(v.x); A[4*i+1] = -__expf(v.y);
            A[4*i+2] = -__expf(v.z); A[4*i+3] = -__expf(v.w);
        }
    }
    float h[16];
    {
        size_t cidx = ((((size_t)b * NCh + c) * Ddim) + d) * 16;
        const float4* hi = (const float4*)(hin + cidx);
        float4 h0 = hi[0], h1 = hi[1], h2 = hi[2], h3 = hi[3];
        h[0]=h0.x; h[1]=h0.y; h[2]=h0.z; h[3]=h0.w;
        h[4]=h1.x; h[5]=h1.y; h[6]=h1.z; h[7]=h1.w;
        h[8]=h2.x; h[9]=h2.y; h[10]=h2.z; h[11]=h2.w;
        h[12]=h3.x; h[13]=h3.y; h[14]=h3.z; h[15]=h3.w;
    }
    float Dd = D_ssm[d];

    size_t base = ((size_t)(b * Sdim + c * LCh)) * Ddim + d;
    const float* dbcrow = dbc + ((size_t)(b * Sdim + c * LCh)) * 64 + 32;

    #pragma unroll 2
    for (int i = 0; i < LCh; ++i) {
        float dlt = delta[base + (size_t)i * Ddim];
        float bw  = bwd [base + (size_t)i * Ddim];
        float z1v = z1  [base + (size_t)i * Ddim];
        float xv  = x   [base + (size_t)i * Ddim];
        float4 B0 = *(const float4*)(dbcrow + i * 64 + 0);
        float4 B1 = *(const float4*)(dbcrow + i * 64 + 4);
        float4 B2 = *(const float4*)(dbcrow + i * 64 + 8);
        float4 B3 = *(const float4*)(dbcrow + i * 64 + 12);
        float4 C0 = *(const float4*)(dbcrow + i * 64 + 16);
        float4 C1 = *(const float4*)(dbcrow + i * 64 + 20);
        float4 C2 = *(const float4*)(dbcrow + i * 64 + 24);
        float4 C3 = *(const float4*)(dbcrow + i * 64 + 28);
        float Bv[16] = {B0.x,B0.y,B0.z,B0.w, B1.x,B1.y,B1.z,B1.w,
                        B2.x,B2.y,B2.z,B2.w, B3.x,B3.y,B3.z,B3.w};
        float Cv[16] = {C0.x,C0.y,C0.z,C0.w, C1.x,C1.y,C1.z,C1.w,
                        C2.x,C2.y,C2.z,C2.w, C3.x,C3.y,C3.z,C3.w};
        float xb = dlt * bw;
        float y  = Dd * bw;
        #pragma unroll
        for (int n = 0; n < 16; ++n) {
            h[n] = fmaf(__expf(dlt * A[n]), h[n], xb * Bv[n]);
            y = fmaf(h[n], Cv[n], y);
        }
        float silu = z1v / (1.f + __expf(-z1v));
        out[base + (size_t)i * Ddim] = fmaf(z1v + y, silu, xv);
    }
}

// ---------------------------------------------------------------------------
extern "C" void kernel_launch(void* const* d_in, const int* in_sizes, int n_in,
                              void* d_out, int out_size, void* d_ws, size_t ws_size,
                              hipStream_t stream) {
    const float* x      = (const float*)d_in[0];
    const float* gamma  = (const float*)d_in[1];
    const float* beta   = (const float*)d_in[2];
    const float* W_proj = (const float*)d_in[3];
    const float* b_proj = (const float*)d_in[4];
    // d_in[5]=W_fwd, d_in[6]=b_fwd dead in reference (x1_ssm unused)
    const float* W_bwd  = (const float*)d_in[7];
    const float* b_bwd  = (const float*)d_in[8];
    const float* W_dbc  = (const float*)d_in[9];
    const float* W_dt   = (const float*)d_in[10];
    const float* b_dt   = (const float*)d_in[11];
    const float* A_log  = (const float*)d_in[12];
    const float* D_ssm  = (const float*)d_in[13];
    float* out = (float*)d_out;

    char* p = (char*)d_ws;
    ushort* xn_bf   = (ushort*)p;                        // [0,8M)
    ushort* z1_bf   = (ushort*)(p + (8ull  << 20));      // [8,16M)
    float*  delta   = (float*) p;                        // [0,16M)  (xn_bf,z1_bf dead by then)
    float*  z1      = (float*)(p + (16ull << 20));       // [16,32M)
    ushort* bwd_bf  = (ushort*)(p + (32ull << 20));      // [32,40M)
    float*  dbc     = (float*)(p + (40ull << 20));       // [40,42M)
    float*  hend    = (float*)(p + (42ull << 20));       // [42,50M)
    float*  sdbuf   = (float*)(p + (50ull << 20));       // 512 KB
    ushort* Wt_proj = (ushort*)(p + (51ull << 20));      // 512 KB
    ushort* Wt_bwd  = Wt_proj + (size_t)Ddim * Ddim;     // 512 KB
    ushort* Wt_dbc  = Wt_bwd  + (size_t)Ddim * Ddim;     // 64 KB
    float*  bwd     = out;                               // bwd lives in d_out

    // 0. weight transposes -> bf16 [N][K]
    transpose_bf16<<<dim3(16, 16), dim3(256), 0, stream>>>(W_proj, Wt_proj, Ddim, Ddim);
    transpose_bf16<<<dim3(16, 16), dim3(256), 0, stream>>>(W_bwd,  Wt_bwd,  Ddim, Ddim);
    transpose_bf16<<<dim3(2, 16),  dim3(256), 0, stream>>>(W_dbc,  Wt_dbc,  Ddim, 64);
    // 1. LayerNorm -> bf16 xn
    ln_kernel<<<dim3(TOK / 4), dim3(256), 0, stream>>>(x, gamma, beta, xn_bf);
    // 2. z1 = xn @ W_proj + b_proj  (fp32 + bf16 outputs)
    gemm_mfma_128<<<dim3(Ddim / 128, TOK / 128), dim3(256), 0, stream>>>(
        xn_bf, Wt_proj, b_proj, z1, z1_bf, Ddim, Ddim);
    // 3. bwd = z1 @ W_bwd + b_bwd  (fp32 into d_out + bf16)
    gemm_mfma_128<<<dim3(Ddim / 128, TOK / 128), dim3(256), 0, stream>>>(
        z1_bf, Wt_bwd, b_bwd, bwd, bwd_bf, Ddim, Ddim);
    // 4. dbc = bwd @ W_dbc
    gemm_mfma_n64<<<dim3(1, TOK / 128), dim3(256), 0, stream>>>(bwd_bf, Wt_dbc, dbc, Ddim);
    // 5. delta = softplus(dbc[:, :32] @ W_dt + b_dt)
    delta_kernel2<<<dim3(TOK / 64), dim3(256), 0, stream>>>(dbc, W_dt, b_dt, delta);
    // 6. chunked scan
    scan_pass1<<<dim3(2, NCh, Bb), dim3(256), 0, stream>>>(delta, bwd, dbc, A_log, hend, sdbuf);
    scan_pass2<<<dim3(Bb * Ddim * Nn16 / 256), dim3(256), 0, stream>>>(hend, sdbuf, A_log);
    scan_pass3<<<dim3(2, NCh, Bb), dim3(256), 0, stream>>>(delta, bwd, dbc, z1, x, A_log, D_ssm, hend, out);
}

// Round 4
// 223.825 us; speedup vs baseline: 3.1379x; 1.2160x over previous
//
#include <hip/hip_runtime.h>
#include <hip/hip_bf16.h>
#include <math.h>

// Problem dims
#define Bb 4
#define Sdim 2048
#define Ddim 512
#define RANK 32
#define Nn16 16
#define TOK (Bb * Sdim)   // 8192
#define NCh 64            // chunks along S
#define LCh (Sdim / NCh)  // 32 steps per chunk

using bf16x8 = __attribute__((ext_vector_type(8))) __bf16;
using f32x4  = __attribute__((ext_vector_type(4))) float;

__device__ __forceinline__ unsigned short f2bf(float f) {
    unsigned int u = __float_as_uint(f);
    u += 0x7fffu + ((u >> 16) & 1u);
    return (unsigned short)(u >> 16);
}

// async global->LDS, 16B per lane; lds base must be wave-uniform
#define GLD16(g, l) __builtin_amdgcn_global_load_lds( \
    (const __attribute__((address_space(1))) void*)(g), \
    (__attribute__((address_space(3))) void*)(l), 16, 0, 0)

// ---------------------------------------------------------------------------
// LayerNorm -> bf16 output. One wave per row of 512, 4 rows / 256-thr block.
// ---------------------------------------------------------------------------
__global__ void ln_kernel(const float* __restrict__ x, const float* __restrict__ gamma,
                          const float* __restrict__ beta, ushort* __restrict__ xn) {
    int row = blockIdx.x * 4 + (threadIdx.x >> 6);
    int lane = threadIdx.x & 63;
    const float4* xr = (const float4*)(x + (size_t)row * Ddim);
    float4 v0 = xr[lane];
    float4 v1 = xr[lane + 64];
    float s = v0.x + v0.y + v0.z + v0.w + v1.x + v1.y + v1.z + v1.w;
    float q = v0.x*v0.x + v0.y*v0.y + v0.z*v0.z + v0.w*v0.w
            + v1.x*v1.x + v1.y*v1.y + v1.z*v1.z + v1.w*v1.w;
    #pragma unroll
    for (int m = 1; m <= 32; m <<= 1) { s += __shfl_xor(s, m); q += __shfl_xor(q, m); }
    float mu = s * (1.0f / Ddim);
    float var = q * (1.0f / Ddim) - mu * mu;
    float rs = rsqrtf(var + 1e-5f);
    const float4* g4 = (const float4*)gamma;
    const float4* b4 = (const float4*)beta;
    float4 g0 = g4[lane], g1 = g4[lane + 64];
    float4 be0 = b4[lane], be1 = b4[lane + 64];
    ushort4 u0, u1;
    u0.x = f2bf((v0.x - mu) * rs * g0.x + be0.x);
    u0.y = f2bf((v0.y - mu) * rs * g0.y + be0.y);
    u0.z = f2bf((v0.z - mu) * rs * g0.z + be0.z);
    u0.w = f2bf((v0.w - mu) * rs * g0.w + be0.w);
    u1.x = f2bf((v1.x - mu) * rs * g1.x + be1.x);
    u1.y = f2bf((v1.y - mu) * rs * g1.y + be1.y);
    u1.z = f2bf((v1.z - mu) * rs * g1.z + be1.z);
    u1.w = f2bf((v1.w - mu) * rs * g1.w + be1.w);
    *(ushort4*)(xn + (size_t)row * Ddim + lane * 4) = u0;
    *(ushort4*)(xn + (size_t)row * Ddim + 256 + lane * 4) = u1;
}

// ---------------------------------------------------------------------------
// Transpose fp32 [K][N] -> bf16 [N][K]
// ---------------------------------------------------------------------------
__global__ void transpose_bf16(const float* __restrict__ in, ushort* __restrict__ out,
                               int K, int N) {
    __shared__ float t[32][33];
    int bx = blockIdx.x * 32, by = blockIdx.y * 32;   // bx: N, by: K
    int x = threadIdx.x & 31, y = threadIdx.x >> 5;   // 256 threads, y=0..7
    #pragma unroll
    for (int yy = y; yy < 32; yy += 8)
        t[yy][x] = in[(size_t)(by + yy) * N + bx + x];
    __syncthreads();
    #pragma unroll
    for (int yy = y; yy < 32; yy += 8)
        out[(size_t)(bx + yy) * K + by + x] = f2bf(t[x][yy]);
}

// ---------------------------------------------------------------------------
// bf16 MFMA GEMM, 128x128 tile, BK=32, B given transposed [N][K].
// C fp32 (+bias), optional Cb bf16 mirror.
// Layouts (m89/m97-verified): A-frag A[m=lane&15][k=quad*8+j];
// B^T-frag identical; C/D col=lane&15, row=quad*4+reg.
// ---------------------------------------------------------------------------
__global__ __launch_bounds__(256) void gemm_mfma_128(
    const ushort* __restrict__ A,  // [M][K] bf16
    const ushort* __restrict__ Bt, // [N][K] bf16
    const float* __restrict__ bias,
    float* __restrict__ C, ushort* __restrict__ Cb,
    int Nw, int K)
{
    __shared__ __align__(16) ushort As[128 * 32];
    __shared__ __align__(16) ushort Bs[128 * 32];
    int tid = threadIdx.x, w = tid >> 6, lane = tid & 63;
    int bm = blockIdx.y * 128, bn = blockIdx.x * 128;
    int wm = (w & 1) * 64, wn = (w >> 1) * 64;
    int quad = lane >> 4, l16 = lane & 15;
    int srow = lane >> 2, schunk = (lane & 3) * 8;   // staging: 16 rows x 4 chunks
    f32x4 acc[4][4] = {};

    for (int k0 = 0; k0 < K; k0 += 32) {
        __syncthreads();   // prior iter's consumers done
        #pragma unroll
        for (int s = 0; s < 2; ++s) {
            int r = w * 32 + s * 16;   // wave-uniform LDS base
            GLD16(A  + (size_t)(bm + r + srow) * K + k0 + schunk, &As[r * 32]);
            GLD16(Bt + (size_t)(bn + r + srow) * K + k0 + schunk, &Bs[r * 32]);
        }
        __syncthreads();   // compiler drains vmcnt before barrier
        bf16x8 af[4], bfr[4];
        #pragma unroll
        for (int i = 0; i < 4; ++i)
            af[i] = *(const bf16x8*)(const void*)&As[(wm + 16 * i + l16) * 32 + quad * 8];
        #pragma unroll
        for (int j = 0; j < 4; ++j)
            bfr[j] = *(const bf16x8*)(const void*)&Bs[(wn + 16 * j + l16) * 32 + quad * 8];
        #pragma unroll
        for (int i = 0; i < 4; ++i)
            #pragma unroll
            for (int j = 0; j < 4; ++j)
                acc[i][j] = __builtin_amdgcn_mfma_f32_16x16x32_bf16(af[i], bfr[j], acc[i][j], 0, 0, 0);
    }

    #pragma unroll
    for (int i = 0; i < 4; ++i) {
        int row = bm + wm + 16 * i + quad * 4;
        #pragma unroll
        for (int j = 0; j < 4; ++j) {
            int col = bn + wn + 16 * j + l16;
            float bv = bias ? bias[col] : 0.f;
            #pragma unroll
            for (int r = 0; r < 4; ++r) {
                float v = acc[i][j][r] + bv;
                C[(size_t)(row + r) * Nw + col] = v;
                if (Cb) Cb[(size_t)(row + r) * Nw + col] = f2bf(v);
            }
        }
    }
}

// ---------------------------------------------------------------------------
// bf16 MFMA GEMM, 128x64 tile (for dbc: N=64). fp32 out + bf16 mirror.
// ---------------------------------------------------------------------------
__global__ __launch_bounds__(256) void gemm_mfma_n64(
    const ushort* __restrict__ A,  // [M][K]
    const ushort* __restrict__ Bt, // [64][K]
    float* __restrict__ C, ushort* __restrict__ Cb, int K)
{
    __shared__ __align__(16) ushort As[128 * 32];
    __shared__ __align__(16) ushort Bs[64 * 32];
    int tid = threadIdx.x, w = tid >> 6, lane = tid & 63;
    int bm = blockIdx.y * 128;
    int wm = w * 32;
    int quad = lane >> 4, l16 = lane & 15;
    int srow = lane >> 2, schunk = (lane & 3) * 8;
    f32x4 acc[2][4] = {};

    for (int k0 = 0; k0 < K; k0 += 32) {
        __syncthreads();
        #pragma unroll
        for (int s = 0; s < 2; ++s) {
            int r = w * 32 + s * 16;
            GLD16(A + (size_t)(bm + r + srow) * K + k0 + schunk, &As[r * 32]);
        }
        {
            int r = w * 16;
            GLD16(Bt + (size_t)(r + srow) * K + k0 + schunk, &Bs[r * 32]);
        }
        __syncthreads();
        bf16x8 af[2], bfr[4];
        #pragma unroll
        for (int i = 0; i < 2; ++i)
            af[i] = *(const bf16x8*)(const void*)&As[(wm + 16 * i + l16) * 32 + quad * 8];
        #pragma unroll
        for (int j = 0; j < 4; ++j)
            bfr[j] = *(const bf16x8*)(const void*)&Bs[(16 * j + l16) * 32 + quad * 8];
        #pragma unroll
        for (int i = 0; i < 2; ++i)
            #pragma unroll
            for (int j = 0; j < 4; ++j)
                acc[i][j] = __builtin_amdgcn_mfma_f32_16x16x32_bf16(af[i], bfr[j], acc[i][j], 0, 0, 0);
    }
    #pragma unroll
    for (int i = 0; i < 2; ++i) {
        int row = bm + wm + 16 * i + quad * 4;
        #pragma unroll
        for (int j = 0; j < 4; ++j) {
            int col = 16 * j + l16;
            #pragma unroll
            for (int r = 0; r < 4; ++r) {
                float v = acc[i][j][r];
                C [(size_t)(row + r) * 64 + col] = v;
                Cb[(size_t)(row + r) * 64 + col] = f2bf(v);
            }
        }
    }
}

// ---------------------------------------------------------------------------
// delta = softplus(dbc[:, :32] @ W_dt + b_dt) as a K=32 single-step MFMA GEMM.
// A = dbc_bf [M][64] (cols 0..31 used), Bt = W_dt^T bf16 [512][32].
// 128x128 tile, fused bias + softplus epilogue, fp32 out.
// ---------------------------------------------------------------------------
__device__ __forceinline__ float softplus_f(float v) {
    return v > 20.f ? v : log1pf(__expf(v));
}

__global__ __launch_bounds__(256) void gemm_delta(
    const ushort* __restrict__ A,   // dbc_bf [M][64]
    const ushort* __restrict__ Bt,  // [512][32]
    const float* __restrict__ b_dt,
    float* __restrict__ delta)
{
    __shared__ __align__(16) ushort As[128 * 32];
    __shared__ __align__(16) ushort Bs[128 * 32];
    int tid = threadIdx.x, w = tid >> 6, lane = tid & 63;
    int bm = blockIdx.y * 128, bn = blockIdx.x * 128;
    int wm = (w & 1) * 64, wn = (w >> 1) * 64;
    int quad = lane >> 4, l16 = lane & 15;
    int srow = lane >> 2, schunk = (lane & 3) * 8;

    #pragma unroll
    for (int s = 0; s < 2; ++s) {
        int r = w * 32 + s * 16;
        GLD16(A  + (size_t)(bm + r + srow) * 64 + schunk, &As[r * 32]);  // first 32 cols
        GLD16(Bt + (size_t)(bn + r + srow) * 32 + schunk, &Bs[r * 32]);
    }
    __syncthreads();

    bf16x8 af[4], bfr[4];
    #pragma unroll
    for (int i = 0; i < 4; ++i)
        af[i] = *(const bf16x8*)(const void*)&As[(wm + 16 * i + l16) * 32 + quad * 8];
    #pragma unroll
    for (int j = 0; j < 4; ++j)
        bfr[j] = *(const bf16x8*)(const void*)&Bs[(wn + 16 * j + l16) * 32 + quad * 8];
    f32x4 acc[4][4] = {};
    #pragma unroll
    for (int i = 0; i < 4; ++i)
        #pragma unroll
        for (int j = 0; j < 4; ++j)
            acc[i][j] = __builtin_amdgcn_mfma_f32_16x16x32_bf16(af[i], bfr[j], acc[i][j], 0, 0, 0);

    #pragma unroll
    for (int i = 0; i < 4; ++i) {
        int row = bm + wm + 16 * i + quad * 4;
        #pragma unroll
        for (int j = 0; j < 4; ++j) {
            int col = bn + wn + 16 * j + l16;
            float bv = b_dt[col];
            #pragma unroll
            for (int r = 0; r < 4; ++r)
                delta[(size_t)(row + r) * Ddim + col] = softplus_f(acc[i][j][r] + bv);
        }
    }
}

// ---------------------------------------------------------------------------
// Chunked parallel scan.
// ---------------------------------------------------------------------------
__global__ __launch_bounds__(256) void scan_pass1(
    const float* __restrict__ delta, const float* __restrict__ bwd,
    const float* __restrict__ dbc, const float* __restrict__ A_log,
    float* __restrict__ hend, float* __restrict__ sdbuf)
{
    int d = (blockIdx.x << 8) + threadIdx.x;
    int c = blockIdx.y;
    int b = blockIdx.z;

    float A[16];
    {
        const float4* al = (const float4*)(A_log + (size_t)d * 16);
        #pragma unroll
        for (int i = 0; i < 4; ++i) {
            float4 v = al[i];
            A[4*i+0] = -__expf(v.x); A[4*i+1] = -__expf(v.y);
            A[4*i+2] = -__expf(v.z); A[4*i+3] = -__expf(v.w);
        }
    }
    float h[16];
    #pragma unroll
    for (int n = 0; n < 16; ++n) h[n] = 0.f;
    float sd = 0.f;

    size_t base = ((size_t)(b * Sdim + c * LCh)) * Ddim + d;
    const float* dbcrow = dbc + ((size_t)(b * Sdim + c * LCh)) * 64 + 32;

    #pragma unroll 2
    for (int i = 0; i < LCh; ++i) {
        float dlt = delta[base + (size_t)i * Ddim];
        float bw  = bwd [base + (size_t)i * Ddim];
        float4 B0 = *(const float4*)(dbcrow + i * 64 + 0);
        float4 B1 = *(const float4*)(dbcrow + i * 64 + 4);
        float4 B2 = *(const float4*)(dbcrow + i * 64 + 8);
        float4 B3 = *(const float4*)(dbcrow + i * 64 + 12);
        sd += dlt;
        float xb = dlt * bw;
        float Bv[16] = {B0.x,B0.y,B0.z,B0.w, B1.x,B1.y,B1.z,B1.w,
                        B2.x,B2.y,B2.z,B2.w, B3.x,B3.y,B3.z,B3.w};
        #pragma unroll
        for (int n = 0; n < 16; ++n)
            h[n] = fmaf(__expf(dlt * A[n]), h[n], xb * Bv[n]);
    }
    size_t cidx = ((((size_t)b * NCh + c) * Ddim) + d) * 16;
    float4* ho = (float4*)(hend + cidx);
    ho[0] = make_float4(h[0],  h[1],  h[2],  h[3]);
    ho[1] = make_float4(h[4],  h[5],  h[6],  h[7]);
    ho[2] = make_float4(h[8],  h[9],  h[10], h[11]);
    ho[3] = make_float4(h[12], h[13], h[14], h[15]);
    sdbuf[((size_t)b * NCh + c) * Ddim + d] = sd;
}

// carry combine, 8-wide software pipeline: loads + exp are hin-independent,
// only the final fma chains.
__global__ __launch_bounds__(256) void scan_pass2(
    float* __restrict__ hend, const float* __restrict__ sdbuf,
    const float* __restrict__ A_log)
{
    int gl = blockIdx.x * 256 + threadIdx.x;
    int b = gl >> 13;
    int r = gl & 8191;
    int d = r >> 4;
    float A = -__expf(A_log[r]);
    float hin = 0.f;
    for (int c0 = 0; c0 < NCh; c0 += 8) {
        float he[8], dec[8];
        #pragma unroll
        for (int u = 0; u < 8; ++u) {
            size_t idx = (((size_t)b * NCh + c0 + u) * Ddim) * 16 + r;
            he[u]  = hend[idx];
            dec[u] = __expf(A * sdbuf[((size_t)b * NCh + c0 + u) * Ddim + d]);
        }
        #pragma unroll
        for (int u = 0; u < 8; ++u) {
            size_t idx = (((size_t)b * NCh + c0 + u) * Ddim) * 16 + r;
            hend[idx] = hin;
            hin = fmaf(dec[u], hin, he[u]);
        }
    }
}

// bwd/out alias (bwd lives in d_out); read-before-write per exclusive (t,d).
__global__ __launch_bounds__(256) void scan_pass3(
    const float* __restrict__ delta, const float* bwd,
    const float* __restrict__ dbc, const float* __restrict__ z1,
    const float* __restrict__ x, const float* __restrict__ A_log,
    const float* __restrict__ D_ssm, const float* __restrict__ hin,
    float* out)
{
    int d = (blockIdx.x << 8) + threadIdx.x;
    int c = blockIdx.y;
    int b = blockIdx.z;

    float A[16];
    {
        const float4* al = (const float4*)(A_log + (size_t)d * 16);
        #pragma unroll
        for (int i = 0; i < 4; ++i) {
            float4 v = al[i];
            A[4*i+0] = -__expf(v.x); A[4*i+1] = -__expf(v.y);
            A[4*i+2] = -__expf(v.z); A[4*i+3] = -__expf(v.w);
        }
    }
    float h[16];
    {
        size_t cidx = ((((size_t)b * NCh + c) * Ddim) + d) * 16;
        const float4* hi = (const float4*)(hin + cidx);
        float4 h0 = hi[0], h1 = hi[1], h2 = hi[2], h3 = hi[3];
        h[0]=h0.x; h[1]=h0.y; h[2]=h0.z; h[3]=h0.w;
        h[4]=h1.x; h[5]=h1.y; h[6]=h1.z; h[7]=h1.w;
        h[8]=h2.x; h[9]=h2.y; h[10]=h2.z; h[11]=h2.w;
        h[12]=h3.x; h[13]=h3.y; h[14]=h3.z; h[15]=h3.w;
    }
    float Dd = D_ssm[d];

    size_t base = ((size_t)(b * Sdim + c * LCh)) * Ddim + d;
    const float* dbcrow = dbc + ((size_t)(b * Sdim + c * LCh)) * 64 + 32;

    #pragma unroll 2
    for (int i = 0; i < LCh; ++i) {
        float dlt = delta[base + (size_t)i * Ddim];
        float bw  = bwd [base + (size_t)i * Ddim];
        float z1v = z1  [base + (size_t)i * Ddim];
        float xv  = x   [base + (size_t)i * Ddim];
        float4 B0 = *(const float4*)(dbcrow + i * 64 + 0);
        float4 B1 = *(const float4*)(dbcrow + i * 64 + 4);
        float4 B2 = *(const float4*)(dbcrow + i * 64 + 8);
        float4 B3 = *(const float4*)(dbcrow + i * 64 + 12);
        float4 C0 = *(const float4*)(dbcrow + i * 64 + 16);
        float4 C1 = *(const float4*)(dbcrow + i * 64 + 20);
        float4 C2 = *(const float4*)(dbcrow + i * 64 + 24);
        float4 C3 = *(const float4*)(dbcrow + i * 64 + 28);
        float Bv[16] = {B0.x,B0.y,B0.z,B0.w, B1.x,B1.y,B1.z,B1.w,
                        B2.x,B2.y,B2.z,B2.w, B3.x,B3.y,B3.z,B3.w};
        float Cv[16] = {C0.x,C0.y,C0.z,C0.w, C1.x,C1.y,C1.z,C1.w,
                        C2.x,C2.y,C2.z,C2.w, C3.x,C3.y,C3.z,C3.w};
        float xb = dlt * bw;
        float y  = Dd * bw;
        #pragma unroll
        for (int n = 0; n < 16; ++n) {
            h[n] = fmaf(__expf(dlt * A[n]), h[n], xb * Bv[n]);
            y = fmaf(h[n], Cv[n], y);
        }
        float silu = z1v / (1.f + __expf(-z1v));
        out[base + (size_t)i * Ddim] = fmaf(z1v + y, silu, xv);
    }
}

// ---------------------------------------------------------------------------
extern "C" void kernel_launch(void* const* d_in, const int* in_sizes, int n_in,
                              void* d_out, int out_size, void* d_ws, size_t ws_size,
                              hipStream_t stream) {
    const float* x      = (const float*)d_in[0];
    const float* gamma  = (const float*)d_in[1];
    const float* beta   = (const float*)d_in[2];
    const float* W_proj = (const float*)d_in[3];
    const float* b_proj = (const float*)d_in[4];
    // d_in[5]=W_fwd, d_in[6]=b_fwd dead in reference (x1_ssm unused)
    const float* W_bwd  = (const float*)d_in[7];
    const float* b_bwd  = (const float*)d_in[8];
    const float* W_dbc  = (const float*)d_in[9];
    const float* W_dt   = (const float*)d_in[10];
    const float* b_dt   = (const float*)d_in[11];
    const float* A_log  = (const float*)d_in[12];
    const float* D_ssm  = (const float*)d_in[13];
    float* out = (float*)d_out;

    char* p = (char*)d_ws;
    ushort* xn_bf   = (ushort*)p;                        // [0,8M)
    ushort* z1_bf   = (ushort*)(p + (8ull  << 20));      // [8,16M)
    float*  delta   = (float*) p;                        // [0,16M)  (xn_bf,z1_bf dead by then)
    float*  z1      = (float*)(p + (16ull << 20));       // [16,32M)
    ushort* bwd_bf  = (ushort*)(p + (32ull << 20));      // [32,40M)
    float*  dbc     = (float*)(p + (40ull << 20));       // [40,42M)
    float*  hend    = (float*)(p + (42ull << 20));       // [42,50M)
    ushort* dbc_bf  = (ushort*)(p + (42ull << 20));      // 1MB; dead before pass1 writes hend
    float*  sdbuf   = (float*)(p + (50ull << 20));       // 512 KB
    ushort* Wt_proj = (ushort*)(p + (51ull << 20));      // 512 KB
    ushort* Wt_bwd  = Wt_proj + (size_t)Ddim * Ddim;     // 512 KB
    ushort* Wt_dbc  = Wt_bwd  + (size_t)Ddim * Ddim;     // 64 KB
    ushort* Wt_dt   = Wt_dbc  + (size_t)Ddim * 64;       // 32 KB
    float*  bwd     = out;                               // bwd lives in d_out

    // 0. weight transposes -> bf16 [N][K]
    transpose_bf16<<<dim3(16, 16), dim3(256), 0, stream>>>(W_proj, Wt_proj, Ddim, Ddim);
    transpose_bf16<<<dim3(16, 16), dim3(256), 0, stream>>>(W_bwd,  Wt_bwd,  Ddim, Ddim);
    transpose_bf16<<<dim3(2, 16),  dim3(256), 0, stream>>>(W_dbc,  Wt_dbc,  Ddim, 64);
    transpose_bf16<<<dim3(16, 1),  dim3(256), 0, stream>>>(W_dt,   Wt_dt,   RANK, Ddim);
    // 1. LayerNorm -> bf16 xn
    ln_kernel<<<dim3(TOK / 4), dim3(256), 0, stream>>>(x, gamma, beta, xn_bf);
    // 2. z1 = xn @ W_proj + b_proj  (fp32 + bf16 outputs)
    gemm_mfma_128<<<dim3(Ddim / 128, TOK / 128), dim3(256), 0, stream>>>(
        xn_bf, Wt_proj, b_proj, z1, z1_bf, Ddim, Ddim);
    // 3. bwd = z1 @ W_bwd + b_bwd  (fp32 into d_out + bf16)
    gemm_mfma_128<<<dim3(Ddim / 128, TOK / 128), dim3(256), 0, stream>>>(
        z1_bf, Wt_bwd, b_bwd, bwd, bwd_bf, Ddim, Ddim);
    // 4. dbc = bwd @ W_dbc (fp32 + bf16)
    gemm_mfma_n64<<<dim3(1, TOK / 128), dim3(256), 0, stream>>>(bwd_bf, Wt_dbc, dbc, dbc_bf, Ddim);
    // 5. delta = softplus(dbc[:, :32] @ W_dt + b_dt) as K=32 MFMA GEMM
    gemm_delta<<<dim3(Ddim / 128, TOK / 128), dim3(256), 0, stream>>>(dbc_bf, Wt_dt, b_dt, delta);
    // 6. chunked scan
    scan_pass1<<<dim3(2, NCh, Bb), dim3(256), 0, stream>>>(delta, bwd, dbc, A_log, hend, sdbuf);
    scan_pass2<<<dim3(Bb * Ddim * Nn16 / 256), dim3(256), 0, stream>>>(hend, sdbuf, A_log);
    scan_pass3<<<dim3(2, NCh, Bb), dim3(256), 0, stream>>>(delta, bwd, dbc, z1, x, A_log, D_ssm, hend, out);
}